// Round 8
// baseline (100.469 us; speedup 1.0000x reference)
//
#include <hip/hip_runtime.h>
#include <hip/hip_cooperative_groups.h>
#include <math.h>

namespace cg = cooperative_groups;

#define B_ 2
#define N_ 20000
#define M_ 1024
#define C_ 256
#define BN_EPS_ 1e-5f

#define NNBLK_PER_B_ 313            // fallback: ceil(20000/64)
#define GEMM_BLOCKS_ 256
#define NN_BLOCKS_   (2 * NNBLK_PER_B_)
#define CPPB_ 157                   // coop: points per NN block (128 blocks/batch)

// index-carrying sorted top-3 insert, strict < keeps earliest (lowest index)
#define INSERT3(dd, ss)                                   \
    {                                                     \
        bool c2_ = (dd) < v2;                             \
        v2 = c2_ ? (dd) : v2;  i2 = c2_ ? (ss) : i2;      \
        bool c1_ = v2 < v1;                               \
        float tv_ = v1; int ti_ = i1;                     \
        v1 = c1_ ? v2 : v1;  i1 = c1_ ? i2 : i1;          \
        v2 = c1_ ? tv_ : v2; i2 = c1_ ? ti_ : i2;         \
        bool c0_ = v1 < v0;                               \
        tv_ = v0; ti_ = i0;                               \
        v0 = c0_ ? v1 : v0;  i0 = c0_ ? i1 : i0;          \
        v1 = c0_ ? tv_ : v1; i1 = c0_ ? ti_ : i1;         \
    }

// ---------------------------------------------------------------------------
// GEMM role body (R5-proven, shared by coop kernel and fallback kernel).
// 256 threads. Writes part[ot][b][j][m].
// ---------------------------------------------------------------------------
__device__ __forceinline__ void gemm_role(
    int bid, int tid, float4* smembuf,
    const float* __restrict__ feat,
    const float* __restrict__ w1f, const float* __restrict__ b1f,
    const float* __restrict__ g1f, const float* __restrict__ be1f,
    const float* __restrict__ mu1f, const float* __restrict__ var1f,
    const float* __restrict__ w2f, const float* __restrict__ b2f,
    const float* __restrict__ w1c, const float* __restrict__ b1c,
    const float* __restrict__ g1c, const float* __restrict__ be1c,
    const float* __restrict__ mu1c, const float* __restrict__ var1c,
    const float* __restrict__ w2c, const float* __restrict__ b2c,
    float* __restrict__ part)
{
    const int mt = bid & 15;
    const int ot = (bid >> 4) & 3;
    const int bh = bid >> 6;
    const int b = bh >> 1, head = bh & 1;

    const float* __restrict__ w1   = head ? w1c   : w1f;
    const float* __restrict__ b1   = head ? b1c   : b1f;
    const float* __restrict__ g1   = head ? g1c   : g1f;
    const float* __restrict__ be1  = head ? be1c  : be1f;
    const float* __restrict__ mu1  = head ? mu1c  : mu1f;
    const float* __restrict__ var1 = head ? var1c : var1f;
    const float* __restrict__ w2   = head ? w2c   : w2f;
    const float* __restrict__ b2   = head ? b2c   : b2f;
    const int nj = head ? 3 : 2;

    float* base = (float*)smembuf;
    float (*sW)[68]      = (float(*)[68])base;             // 16x68
    float (*sF)[64]      = (float(*)[64])(base + 1088);    // 16x64
    float (*sred)[3][68] = (float(*)[3][68])(base + 2112); // 16x3x68

    const int tm = tid & 15;
    const int to = tid >> 4;
    const int m0 = mt * 64, o0 = ot * 64;

    const int so  = tid >> 2;
    const int sc4 = (tid & 3) << 2;
    const float sscale = g1[o0 + so] * rsqrtf(var1[o0 + so] + BN_EPS_);
    const int fc = tid >> 4;
    const int fm = (tid & 15) << 2;

    const float* __restrict__ wrow = w1 + (size_t)(o0 + so) * C_ + sc4;
    const float* __restrict__ frow = feat + ((size_t)b * C_ + fc) * M_ + m0 + fm;

    float4 wv = *(const float4*)(wrow);
    float4 fv = *(const float4*)(frow);

    float acc[4][4] = {};

    for (int c0 = 0; c0 < C_; c0 += 16) {
        __syncthreads();
        sW[sc4 + 0][so] = wv.x * sscale;
        sW[sc4 + 1][so] = wv.y * sscale;
        sW[sc4 + 2][so] = wv.z * sscale;
        sW[sc4 + 3][so] = wv.w * sscale;
        *(float4*)&sF[fc][fm] = fv;
        __syncthreads();
        const int cn = (c0 + 16 < C_) ? c0 + 16 : c0;
        wv = *(const float4*)(wrow + cn);
        fv = *(const float4*)(frow + (size_t)cn * M_);
        #pragma unroll
        for (int cc = 0; cc < 16; ++cc) {
            float4 w4 = *(const float4*)&sW[cc][to << 2];
            float4 f4 = *(const float4*)&sF[cc][tm << 2];
            float wr[4] = {w4.x, w4.y, w4.z, w4.w};
            float fr[4] = {f4.x, f4.y, f4.z, f4.w};
            #pragma unroll
            for (int i = 0; i < 4; ++i)
                #pragma unroll
                for (int j = 0; j < 4; ++j)
                    acc[i][j] = fmaf(wr[i], fr[j], acc[i][j]);
        }
    }

    float r[4][4];
    #pragma unroll
    for (int i = 0; i < 4; ++i) {
        const int o = o0 + (to << 2) + i;
        const float sc = g1[o] * rsqrtf(var1[o] + BN_EPS_);
        const float bb = (b1[o] - mu1[o]) * sc + be1[o];
        #pragma unroll
        for (int jj = 0; jj < 4; ++jj)
            r[i][jj] = fmaxf(acc[i][jj] + bb, 0.f);
    }

    __syncthreads();
    for (int j = 0; j < nj; ++j) {
        float s[4] = {0.f, 0.f, 0.f, 0.f};
        #pragma unroll
        for (int i = 0; i < 4; ++i) {
            const float w = w2[(size_t)j * C_ + o0 + (to << 2) + i];
            #pragma unroll
            for (int jj = 0; jj < 4; ++jj)
                s[jj] = fmaf(w, r[i][jj], s[jj]);
        }
        *(float4*)&sred[to][j][tm << 2] = *(float4*)s;
    }
    __syncthreads();

    if (tid < nj * 64) {
        const int j = tid >> 6, m = tid & 63;
        float a = 0.f;
        #pragma unroll
        for (int t = 0; t < 16; ++t) a += sred[t][j][m];
        if (ot == 0) a += b2[j];
        const int jg = head ? (2 + j) : j;
        part[(((size_t)ot * B_ + b) * 5 + jg) * M_ + m0 + m] = a;
    }
}

// ===========================================================================
// COOP kernel: 512 blocks x 256 threads, single dispatch.
//   blocks [0,256):   GEMM role (verbatim) -> part[], grid.sync, exit
//   blocks [256,512): 3-NN over 157-point slice (3 chunks x R5-proven scan),
//                     q/i in registers, grid.sync, so5 stage + gather -> out
// ===========================================================================
__global__ __launch_bounds__(256) void k_coop(
    const float* __restrict__ pc, const float* __restrict__ seed,
    const float* __restrict__ feat,
    const float* __restrict__ w1f, const float* __restrict__ b1f,
    const float* __restrict__ g1f, const float* __restrict__ be1f,
    const float* __restrict__ mu1f, const float* __restrict__ var1f,
    const float* __restrict__ w2f, const float* __restrict__ b2f,
    const float* __restrict__ w1c, const float* __restrict__ b1c,
    const float* __restrict__ g1c, const float* __restrict__ be1c,
    const float* __restrict__ mu1c, const float* __restrict__ var1c,
    const float* __restrict__ w2c, const float* __restrict__ b2c,
    float* __restrict__ part, float* __restrict__ out)
{
    cg::grid_group gridg = cg::this_grid();
    __shared__ float4 smembuf[1408];          // 22528 B union
    const int bid = blockIdx.x;
    const int tid = threadIdx.x;

    if (bid < GEMM_BLOCKS_) {
        gemm_role(bid, tid, smembuf, feat,
                  w1f, b1f, g1f, be1f, mu1f, var1f, w2f, b2f,
                  w1c, b1c, g1c, be1c, mu1c, var1c, w2c, b2c, part);
        gridg.sync();
        return;
    }

    // ---------------- NN role: 157 points in 3 chunks of 64 ----------------
    const int nb = bid - GEMM_BLOCKS_;        // 0..511-256 -> 0..255
    const int b = nb >> 7;                    // 128 blocks per batch
    const int pbase = (nb & 127) * CPPB_;
    const int pend = (pbase + CPPB_ < N_) ? (pbase + CPPB_) : N_;
    const int wv = tid >> 6, lane = tid & 63;

    float4* sseed = smembuf;                                  // 16384 B
    float* nnb = (float*)(smembuf + M_);
    float (*smd)[64][3] = (float(*)[64][3])nnb;               // 4x64x3
    int   (*smi)[64][3] = (int(*)[64][3])(nnb + 768);

    for (int s = tid; s < M_; s += 256) {
        const float kx = seed[((size_t)b * M_ + s) * 3 + 0];
        const float ky = seed[((size_t)b * M_ + s) * 3 + 1];
        const float kz = seed[((size_t)b * M_ + s) * 3 + 2];
        sseed[s] = make_float4(kx, ky, kz, 0.5f * ((kx * kx + ky * ky) + kz * kz));
    }
    __syncthreads();

    float q0s[3], q1s[3], q2s[3];
    int i0s[3], i1s[3], i2s[3];

    #pragma unroll
    for (int c = 0; c < 3; ++c) {
        const int p = pbase + (c << 6) + lane;
        const int pcl = (p < N_) ? p : (N_ - 1);
        const float ux = pc[((size_t)b * N_ + pcl) * 3 + 0];
        const float uy = pc[((size_t)b * N_ + pcl) * 3 + 1];
        const float uz = pc[((size_t)b * N_ + pcl) * 3 + 2];
        const float un = (ux * ux + uy * uy) + uz * uz;

        float v0 = 3.4e38f, v1 = 3.4e38f, v2 = 3.4e38f;
        int i0 = 0, i1 = 0, i2 = 0;
        const int sb = wv << 8;
        const float4* __restrict__ sp = sseed + sb;
        #pragma unroll 8
        for (int t = 0; t < 256; ++t) {
            const float4 k = sp[t];
            const float d = fmaf(-ux, k.x, fmaf(-uy, k.y, fmaf(-uz, k.z, k.w)));
            INSERT3(d, sb + t);
        }

        smd[wv][lane][0] = v0; smd[wv][lane][1] = v1; smd[wv][lane][2] = v2;
        smi[wv][lane][0] = i0; smi[wv][lane][1] = i1; smi[wv][lane][2] = i2;
        __syncthreads();

        if (wv == 0) {
            #pragma unroll
            for (int w = 1; w < 4; ++w) {
                #pragma unroll
                for (int k = 0; k < 3; ++k) {
                    const float dd = smd[w][lane][k];
                    const int   ss = smi[w][lane][k];
                    INSERT3(dd, ss);
                }
            }
            const float d0 = sqrtf(fmaxf(fmaf(2.f, v0, un), 1e-12f));
            const float d1 = sqrtf(fmaxf(fmaf(2.f, v1, un), 1e-12f));
            const float d2s = sqrtf(fmaxf(fmaf(2.f, v2, un), 1e-12f));
            const float r0 = 1.f / (d0 + 1e-8f);
            const float r1 = 1.f / (d1 + 1e-8f);
            const float r2 = 1.f / (d2s + 1e-8f);
            const float rs = (r0 + r1) + r2;
            q0s[c] = r0 / rs; q1s[c] = r1 / rs; q2s[c] = r2 / rs;
            i0s[c] = i0; i1s[c] = i1; i2s[c] = i2;
        }
        __syncthreads();                 // smd/smi reused next chunk
    }

    gridg.sync();                        // part[] visible device-wide

    // so5 = 4-partial sum of part, staged in LDS (overlays dead sseed)
    float* so5 = (float*)smembuf;        // [5][1024] = 20480 B
    for (int v = tid; v < 5 * M_; v += 256) {
        const int j = v >> 10, m = v & (M_ - 1);
        const float* __restrict__ pp = part + ((size_t)b * 5 + j) * M_ + m;
        so5[v] = (pp[0] + pp[10240]) + (pp[20480] + pp[30720]);
    }
    __syncthreads();

    if (wv == 0) {
        #pragma unroll
        for (int c = 0; c < 3; ++c) {
            const int p = pbase + (c << 6) + lane;
            if (p < pend) {
                #pragma unroll
                for (int j = 0; j < 5; ++j) {
                    const float val = fmaf(q0s[c], so5[(j << 10) + i0s[c]],
                                     fmaf(q1s[c], so5[(j << 10) + i1s[c]],
                                          q2s[c] * so5[(j << 10) + i2s[c]]));
                    out[((size_t)b * 5 + j) * N_ + p] = val;
                }
            }
        }
    }
}

// ===========================================================================
// FALLBACK: R5-proven two-kernel path.
// ===========================================================================
__global__ __launch_bounds__(256) void k_fused(
    const float* __restrict__ pc, const float* __restrict__ seed,
    const float* __restrict__ feat,
    const float* __restrict__ w1f, const float* __restrict__ b1f,
    const float* __restrict__ g1f, const float* __restrict__ be1f,
    const float* __restrict__ mu1f, const float* __restrict__ var1f,
    const float* __restrict__ w2f, const float* __restrict__ b2f,
    const float* __restrict__ w1c, const float* __restrict__ b1c,
    const float* __restrict__ g1c, const float* __restrict__ be1c,
    const float* __restrict__ mu1c, const float* __restrict__ var1c,
    const float* __restrict__ w2c, const float* __restrict__ b2c,
    float* __restrict__ part, uint4* __restrict__ nnres)
{
    __shared__ float4 smembuf[1408];
    const int bid = blockIdx.x;
    const int tid = threadIdx.x;

    if (bid < GEMM_BLOCKS_) {
        gemm_role(bid, tid, smembuf, feat,
                  w1f, b1f, g1f, be1f, mu1f, var1f, w2f, b2f,
                  w1c, b1c, g1c, be1c, mu1c, var1c, w2c, b2c, part);
    } else {
        const int nb = bid - GEMM_BLOCKS_;
        const int b = (nb >= NNBLK_PER_B_) ? 1 : 0;
        const int p0 = (nb - b * NNBLK_PER_B_) << 6;
        const int wv = tid >> 6, lane = tid & 63;

        float4* sseed = smembuf;
        float* nnb = (float*)(smembuf + M_);
        float (*smd)[64][3] = (float(*)[64][3])nnb;
        int   (*smi)[64][3] = (int(*)[64][3])(nnb + 768);

        for (int s = tid; s < M_; s += 256) {
            const float kx = seed[((size_t)b * M_ + s) * 3 + 0];
            const float ky = seed[((size_t)b * M_ + s) * 3 + 1];
            const float kz = seed[((size_t)b * M_ + s) * 3 + 2];
            sseed[s] = make_float4(kx, ky, kz, 0.5f * ((kx * kx + ky * ky) + kz * kz));
        }
        __syncthreads();

        const int p = p0 + lane;
        const int pcl = (p < N_) ? p : (N_ - 1);
        const float ux = pc[((size_t)b * N_ + pcl) * 3 + 0];
        const float uy = pc[((size_t)b * N_ + pcl) * 3 + 1];
        const float uz = pc[((size_t)b * N_ + pcl) * 3 + 2];
        const float un = (ux * ux + uy * uy) + uz * uz;

        float v0 = 3.4e38f, v1 = 3.4e38f, v2 = 3.4e38f;
        int i0 = 0, i1 = 0, i2 = 0;
        const int sb = wv << 8;
        const float4* __restrict__ sp = sseed + sb;
        #pragma unroll 8
        for (int t = 0; t < 256; ++t) {
            const float4 k = sp[t];
            const float d = fmaf(-ux, k.x, fmaf(-uy, k.y, fmaf(-uz, k.z, k.w)));
            INSERT3(d, sb + t);
        }

        smd[wv][lane][0] = v0; smd[wv][lane][1] = v1; smd[wv][lane][2] = v2;
        smi[wv][lane][0] = i0; smi[wv][lane][1] = i1; smi[wv][lane][2] = i2;
        __syncthreads();

        if (wv == 0 && p < N_) {
            #pragma unroll
            for (int w = 1; w < 4; ++w) {
                #pragma unroll
                for (int k = 0; k < 3; ++k) {
                    const float dd = smd[w][lane][k];
                    const int   ss = smi[w][lane][k];
                    INSERT3(dd, ss);
                }
            }
            const float d0 = sqrtf(fmaxf(fmaf(2.f, v0, un), 1e-12f));
            const float d1 = sqrtf(fmaxf(fmaf(2.f, v1, un), 1e-12f));
            const float d2s = sqrtf(fmaxf(fmaf(2.f, v2, un), 1e-12f));
            const float r0 = 1.f / (d0 + 1e-8f);
            const float r1 = 1.f / (d1 + 1e-8f);
            const float r2 = 1.f / (d2s + 1e-8f);
            const float rs = (r0 + r1) + r2;
            const float q0 = r0 / rs, q1 = r1 / rs, q2 = r2 / rs;
            const unsigned pk = (unsigned)i0 | ((unsigned)i1 << 10) | ((unsigned)i2 << 20);
            nnres[(size_t)b * N_ + p] = make_uint4(
                pk, __float_as_uint(q0), __float_as_uint(q1), __float_as_uint(q2));
        }
    }
}

__global__ __launch_bounds__(256) void k_gather(
    const float* __restrict__ part, const uint4* __restrict__ nnres,
    float* __restrict__ out)
{
    const int b = blockIdx.y;
    __shared__ float so5[5][M_];
    for (int v = threadIdx.x; v < 5 * M_; v += 256) {
        const int j = v >> 10, m = v & (M_ - 1);
        const float* __restrict__ pp = part + ((size_t)b * 5 + j) * M_ + m;
        so5[j][m] = (pp[0] + pp[10240]) + (pp[20480] + pp[30720]);
    }
    __syncthreads();

    const int p = (blockIdx.x << 8) + threadIdx.x;
    if (p < N_) {
        const uint4 r = nnres[(size_t)b * N_ + p];
        const int i0 = r.x & 1023, i1 = (r.x >> 10) & 1023, i2 = (r.x >> 20) & 1023;
        const float q0 = __uint_as_float(r.y);
        const float q1 = __uint_as_float(r.z);
        const float q2 = __uint_as_float(r.w);
        #pragma unroll
        for (int j = 0; j < 5; ++j) {
            out[((size_t)b * 5 + j) * N_ + p] =
                fmaf(q0, so5[j][i0], fmaf(q1, so5[j][i1], q2 * so5[j][i2]));
        }
    }
}

// ---------------------------------------------------------------------------
extern "C" void kernel_launch(void* const* d_in, const int* in_sizes, int n_in,
                              void* d_out, int out_size, void* d_ws, size_t ws_size,
                              hipStream_t stream)
{
    const float* pc    = (const float*)d_in[0];
    const float* sxyz  = (const float*)d_in[1];
    const float* feat  = (const float*)d_in[2];
    const float* w1f   = (const float*)d_in[3];
    const float* b1f   = (const float*)d_in[4];
    const float* g1f   = (const float*)d_in[5];
    const float* be1f  = (const float*)d_in[6];
    const float* mu1f  = (const float*)d_in[7];
    const float* var1f = (const float*)d_in[8];
    const float* w2f   = (const float*)d_in[9];
    const float* b2f   = (const float*)d_in[10];
    const float* w1c   = (const float*)d_in[11];
    const float* b1c   = (const float*)d_in[12];
    const float* g1c   = (const float*)d_in[13];
    const float* be1c  = (const float*)d_in[14];
    const float* mu1c  = (const float*)d_in[15];
    const float* var1c = (const float*)d_in[16];
    const float* w2c   = (const float*)d_in[17];
    const float* b2c   = (const float*)d_in[18];

    float* out  = (float*)d_out;
    float* part = (float*)d_ws;                         // 160 KB
    uint4* nnres = (uint4*)((char*)d_ws + 163840);      // fallback only

    void* args[] = {
        (void*)&pc, (void*)&sxyz, (void*)&feat,
        (void*)&w1f, (void*)&b1f, (void*)&g1f, (void*)&be1f, (void*)&mu1f, (void*)&var1f,
        (void*)&w2f, (void*)&b2f,
        (void*)&w1c, (void*)&b1c, (void*)&g1c, (void*)&be1c, (void*)&mu1c, (void*)&var1c,
        (void*)&w2c, (void*)&b2c,
        (void*)&part, (void*)&out
    };
    hipError_t e = hipLaunchCooperativeKernel((const void*)k_coop,
                                              dim3(512), dim3(256),
                                              args, 0, stream);
    if (e != hipSuccess) {
        (void)hipGetLastError();   // clear error; take proven 2-kernel path
        k_fused<<<dim3(GEMM_BLOCKS_ + NN_BLOCKS_), 256, 0, stream>>>(
            pc, sxyz, feat,
            w1f, b1f, g1f, be1f, mu1f, var1f, w2f, b2f,
            w1c, b1c, g1c, be1c, mu1c, var1c, w2c, b2c,
            part, nnres);
        k_gather<<<dim3((N_ + 255) / 256, B_), 256, 0, stream>>>(part, nnres, out);
    }
}

// Round 9
// 35.821 us; speedup vs baseline: 2.8048x; 2.8048x over previous
//
#include <hip/hip_runtime.h>
#include <math.h>

#define B_ 2
#define N_ 20000
#define M_ 1024
#define C_ 256
#define BN_EPS_ 1e-5f

#define NNBLK_PER_B_ 313            // ceil(20000/64)
#define GEMM_BLOCKS_ 256            // 16 mt x 4 ot x 4 bh
#define NN_BLOCKS_   (2 * NNBLK_PER_B_)

// index-carrying sorted top-3 insert, strict < keeps earliest (lowest index).
// Used on the cold merge path only.
#define INSERT3(dd, ss)                                   \
    {                                                     \
        bool c2_ = (dd) < v2;                             \
        v2 = c2_ ? (dd) : v2;  i2 = c2_ ? (ss) : i2;      \
        bool c1_ = v2 < v1;                               \
        float tv_ = v1; int ti_ = i1;                     \
        v1 = c1_ ? v2 : v1;  i1 = c1_ ? i2 : i1;          \
        v2 = c1_ ? tv_ : v2; i2 = c1_ ? ti_ : i2;         \
        bool c0_ = v1 < v0;                               \
        tv_ = v0; ti_ = i0;                               \
        v0 = c0_ ? v1 : v0;  i0 = c0_ ? i1 : i0;          \
        v1 = c0_ ? tv_ : v1; i1 = c0_ ? ti_ : i1;         \
    }

// ---------------------------------------------------------------------------
// Fused kernel: blocks [0,256) run the head GEMMs -> part[],
//               blocks [256,882) run 3-NN -> nnres[] (packed idx + weights).
// R5-proven structure; hot loop uses the slim exact insert (verified
// state-identical to INSERT3, incl. strict-< ties).
// ---------------------------------------------------------------------------
__global__ __launch_bounds__(256) void k_fused(
    const float* __restrict__ pc, const float* __restrict__ seed,
    const float* __restrict__ feat,
    const float* __restrict__ w1f, const float* __restrict__ b1f,
    const float* __restrict__ g1f, const float* __restrict__ be1f,
    const float* __restrict__ mu1f, const float* __restrict__ var1f,
    const float* __restrict__ w2f, const float* __restrict__ b2f,
    const float* __restrict__ w1c, const float* __restrict__ b1c,
    const float* __restrict__ g1c, const float* __restrict__ be1c,
    const float* __restrict__ mu1c, const float* __restrict__ var1c,
    const float* __restrict__ w2c, const float* __restrict__ b2c,
    float* __restrict__ part, uint4* __restrict__ nnres)
{
    __shared__ float4 smembuf[1408];          // 22528 B, union of both roles
    const int bid = blockIdx.x;
    const int tid = threadIdx.x;

    if (bid < GEMM_BLOCKS_) {
        // =================== GEMM role (R5 verbatim) ===================
        const int mt = bid & 15;
        const int ot = (bid >> 4) & 3;
        const int bh = bid >> 6;
        const int b = bh >> 1, head = bh & 1;

        const float* __restrict__ w1   = head ? w1c   : w1f;
        const float* __restrict__ b1   = head ? b1c   : b1f;
        const float* __restrict__ g1   = head ? g1c   : g1f;
        const float* __restrict__ be1  = head ? be1c  : be1f;
        const float* __restrict__ mu1  = head ? mu1c  : mu1f;
        const float* __restrict__ var1 = head ? var1c : var1f;
        const float* __restrict__ w2   = head ? w2c   : w2f;
        const float* __restrict__ b2   = head ? b2c   : b2f;
        const int nj = head ? 3 : 2;

        float* base = (float*)smembuf;
        float (*sW)[68]      = (float(*)[68])base;             // 16x68
        float (*sF)[64]      = (float(*)[64])(base + 1088);    // 16x64
        float (*sred)[3][68] = (float(*)[3][68])(base + 2112); // 16x3x68

        const int tm = tid & 15;
        const int to = tid >> 4;
        const int m0 = mt * 64, o0 = ot * 64;

        const int so  = tid >> 2;
        const int sc4 = (tid & 3) << 2;
        const float sscale = g1[o0 + so] * rsqrtf(var1[o0 + so] + BN_EPS_);
        const int fc = tid >> 4;
        const int fm = (tid & 15) << 2;

        const float* __restrict__ wrow = w1 + (size_t)(o0 + so) * C_ + sc4;
        const float* __restrict__ frow = feat + ((size_t)b * C_ + fc) * M_ + m0 + fm;

        float4 wv = *(const float4*)(wrow);
        float4 fv = *(const float4*)(frow);

        float acc[4][4] = {};

        for (int c0 = 0; c0 < C_; c0 += 16) {
            __syncthreads();
            sW[sc4 + 0][so] = wv.x * sscale;
            sW[sc4 + 1][so] = wv.y * sscale;
            sW[sc4 + 2][so] = wv.z * sscale;
            sW[sc4 + 3][so] = wv.w * sscale;
            *(float4*)&sF[fc][fm] = fv;
            __syncthreads();
            const int cn = (c0 + 16 < C_) ? c0 + 16 : c0;
            wv = *(const float4*)(wrow + cn);
            fv = *(const float4*)(frow + (size_t)cn * M_);
            #pragma unroll
            for (int cc = 0; cc < 16; ++cc) {
                float4 w4 = *(const float4*)&sW[cc][to << 2];
                float4 f4 = *(const float4*)&sF[cc][tm << 2];
                float wr[4] = {w4.x, w4.y, w4.z, w4.w};
                float fr[4] = {f4.x, f4.y, f4.z, f4.w};
                #pragma unroll
                for (int i = 0; i < 4; ++i)
                    #pragma unroll
                    for (int j = 0; j < 4; ++j)
                        acc[i][j] = fmaf(wr[i], fr[j], acc[i][j]);
            }
        }

        float r[4][4];
        #pragma unroll
        for (int i = 0; i < 4; ++i) {
            const int o = o0 + (to << 2) + i;
            const float sc = g1[o] * rsqrtf(var1[o] + BN_EPS_);
            const float bb = (b1[o] - mu1[o]) * sc + be1[o];
            #pragma unroll
            for (int jj = 0; jj < 4; ++jj)
                r[i][jj] = fmaxf(acc[i][jj] + bb, 0.f);
        }

        __syncthreads();
        for (int j = 0; j < nj; ++j) {
            float s[4] = {0.f, 0.f, 0.f, 0.f};
            #pragma unroll
            for (int i = 0; i < 4; ++i) {
                const float w = w2[(size_t)j * C_ + o0 + (to << 2) + i];
                #pragma unroll
                for (int jj = 0; jj < 4; ++jj)
                    s[jj] = fmaf(w, r[i][jj], s[jj]);
            }
            *(float4*)&sred[to][j][tm << 2] = *(float4*)s;
        }
        __syncthreads();

        if (tid < nj * 64) {
            const int j = tid >> 6, m = tid & 63;
            float a = 0.f;
            #pragma unroll
            for (int t = 0; t < 16; ++t) a += sred[t][j][m];
            if (ot == 0) a += b2[j];
            const int jg = head ? (2 + j) : j;
            part[(((size_t)ot * B_ + b) * 5 + jg) * M_ + m0 + m] = a;
        }
    } else {
        // =================== NN role ===================
        const int nb = bid - GEMM_BLOCKS_;
        const int b = (nb >= NNBLK_PER_B_) ? 1 : 0;
        const int p0 = (nb - b * NNBLK_PER_B_) << 6;
        const int wv = tid >> 6, lane = tid & 63;

        float4* sseed = smembuf;                                  // 1024 x 16B
        float* nnb = (float*)(smembuf + M_);
        float (*smd)[64][3] = (float(*)[64][3])nnb;               // 4x64x3
        int   (*smi)[64][3] = (int(*)[64][3])(nnb + 768);

        for (int s = tid; s < M_; s += 256) {
            const float kx = seed[((size_t)b * M_ + s) * 3 + 0];
            const float ky = seed[((size_t)b * M_ + s) * 3 + 1];
            const float kz = seed[((size_t)b * M_ + s) * 3 + 2];
            sseed[s] = make_float4(kx, ky, kz, 0.5f * ((kx * kx + ky * ky) + kz * kz));
        }
        __syncthreads();

        const int p = p0 + lane;
        const int pcl = (p < N_) ? p : (N_ - 1);
        const float ux = pc[((size_t)b * N_ + pcl) * 3 + 0];
        const float uy = pc[((size_t)b * N_ + pcl) * 3 + 1];
        const float uz = pc[((size_t)b * N_ + pcl) * 3 + 2];
        const float un = (ux * ux + uy * uy) + uz * uz;

        float v0 = 3.4e38f, v1 = 3.4e38f, v2 = 3.4e38f;
        int i0 = 0, i1 = 0, i2 = 0;
        const int sb = wv << 8;
        const float4* __restrict__ sp = sseed + sb;
        #pragma unroll 8
        for (int t = 0; t < 256; ++t) {
            const float4 k = sp[t];
            // metric = 0.5|k|^2 - u.k  (monotone in d2 = 2*metric + |u|^2)
            const float d = fmaf(-ux, k.x, fmaf(-uy, k.y, fmaf(-uz, k.z, k.w)));
            // Slim exact insert — state-identical to INSERT3 (verified incl.
            // strict-< ties): 3 cmp vs OLD v's, nested-select indices,
            // med3/med3/min values.
            const bool c0 = d < v0;
            const bool c1 = d < v1;
            const bool c2 = d < v2;
            const int gi = sb + t;
            i2 = c2 ? (c1 ? i1 : gi) : i2;     // uses old i1
            i1 = c1 ? (c0 ? i0 : gi) : i1;     // uses old i0
            i0 = c0 ? gi : i0;
            const float nv1 = __builtin_amdgcn_fmed3f(d, v0, v1);
            const float nv2 = __builtin_amdgcn_fmed3f(d, v1, v2);
            v0 = fminf(d, v0);
            v1 = nv1;
            v2 = nv2;
        }

        smd[wv][lane][0] = v0; smd[wv][lane][1] = v1; smd[wv][lane][2] = v2;
        smi[wv][lane][0] = i0; smi[wv][lane][1] = i1; smi[wv][lane][2] = i2;
        __syncthreads();

        if (wv == 0 && p < N_) {
            #pragma unroll
            for (int w = 1; w < 4; ++w) {
                #pragma unroll
                for (int k = 0; k < 3; ++k) {
                    const float dd = smd[w][lane][k];
                    const int   ss = smi[w][lane][k];
                    INSERT3(dd, ss);
                }
            }
            const float d0 = sqrtf(fmaxf(fmaf(2.f, v0, un), 1e-12f));
            const float d1 = sqrtf(fmaxf(fmaf(2.f, v1, un), 1e-12f));
            const float d2s = sqrtf(fmaxf(fmaf(2.f, v2, un), 1e-12f));
            const float r0 = 1.f / (d0 + 1e-8f);
            const float r1 = 1.f / (d1 + 1e-8f);
            const float r2 = 1.f / (d2s + 1e-8f);
            const float rs = (r0 + r1) + r2;
            const float q0 = r0 / rs, q1 = r1 / rs, q2 = r2 / rs;
            const unsigned pk = (unsigned)i0 | ((unsigned)i1 << 10) | ((unsigned)i2 << 20);
            nnres[(size_t)b * N_ + p] = make_uint4(
                pk, __float_as_uint(q0), __float_as_uint(q1), __float_as_uint(q2));
        }
    }
}

// ---------------------------------------------------------------------------
// Gather epilogue: out[b][j][p] = sum_k q_k * so5[j][idx_k]   (R5 verbatim)
// ---------------------------------------------------------------------------
__global__ __launch_bounds__(256) void k_gather(
    const float* __restrict__ part, const uint4* __restrict__ nnres,
    float* __restrict__ out)
{
    const int b = blockIdx.y;
    __shared__ float so5[5][M_];
    for (int v = threadIdx.x; v < 5 * M_; v += 256) {
        const int j = v >> 10, m = v & (M_ - 1);
        const float* __restrict__ pp = part + ((size_t)b * 5 + j) * M_ + m;
        so5[j][m] = (pp[0] + pp[10240]) + (pp[20480] + pp[30720]);
    }
    __syncthreads();

    const int p = (blockIdx.x << 8) + threadIdx.x;
    if (p < N_) {
        const uint4 r = nnres[(size_t)b * N_ + p];
        const int i0 = r.x & 1023, i1 = (r.x >> 10) & 1023, i2 = (r.x >> 20) & 1023;
        const float q0 = __uint_as_float(r.y);
        const float q1 = __uint_as_float(r.z);
        const float q2 = __uint_as_float(r.w);
        #pragma unroll
        for (int j = 0; j < 5; ++j) {
            out[((size_t)b * 5 + j) * N_ + p] =
                fmaf(q0, so5[j][i0], fmaf(q1, so5[j][i1], q2 * so5[j][i2]));
        }
    }
}

// ---------------------------------------------------------------------------
extern "C" void kernel_launch(void* const* d_in, const int* in_sizes, int n_in,
                              void* d_out, int out_size, void* d_ws, size_t ws_size,
                              hipStream_t stream)
{
    const float* pc    = (const float*)d_in[0];
    const float* sxyz  = (const float*)d_in[1];
    const float* feat  = (const float*)d_in[2];
    const float* w1f   = (const float*)d_in[3];
    const float* b1f   = (const float*)d_in[4];
    const float* g1f   = (const float*)d_in[5];
    const float* be1f  = (const float*)d_in[6];
    const float* mu1f  = (const float*)d_in[7];
    const float* var1f = (const float*)d_in[8];
    const float* w2f   = (const float*)d_in[9];
    const float* b2f   = (const float*)d_in[10];
    const float* w1c   = (const float*)d_in[11];
    const float* b1c   = (const float*)d_in[12];
    const float* g1c   = (const float*)d_in[13];
    const float* be1c  = (const float*)d_in[14];
    const float* mu1c  = (const float*)d_in[15];
    const float* var1c = (const float*)d_in[16];
    const float* w2c   = (const float*)d_in[17];
    const float* b2c   = (const float*)d_in[18];

    float* out  = (float*)d_out;
    float* part = (float*)d_ws;                         // 4*2*5*1024 f32 = 160 KB
    uint4* nnres = (uint4*)((char*)d_ws + 163840);      // 40000 * 16 B

    k_fused<<<dim3(GEMM_BLOCKS_ + NN_BLOCKS_), 256, 0, stream>>>(
        pc, sxyz, feat,
        w1f, b1f, g1f, be1f, mu1f, var1f, w2f, b2f,
        w1c, b1c, g1c, be1c, mu1c, var1c, w2c, b2c,
        part, nnres);

    k_gather<<<dim3((N_ + 255) / 256, B_), 256, 0, stream>>>(part, nnres, out);
}